// Round 6
// baseline (290.276 us; speedup 1.0000x reference)
//
#include <hip/hip_runtime.h>
#include <cmath>

#define NHID 64
#define NMONTH 16384
#define NAGENT 16
#define NROWS (NMONTH*NAGENT)   // 262144
#define NPROTO 24
#define TSEQ 32
#define NACT 12
#define EPS_P  1e-4f
#define EPS_BN 1e-5f
#define EPS_LN 1e-5f

typedef __attribute__((ext_vector_type(8))) short short8;
typedef __attribute__((ext_vector_type(4))) float f32x4;
typedef __attribute__((ext_vector_type(4))) unsigned short us4;
typedef __attribute__((ext_vector_type(8))) unsigned short us8;
typedef unsigned short ushort_t;

#define MFMA(a,b,c) __builtin_amdgcn_mfma_f32_16x16x32_bf16(a,b,c,0,0,0)
#define LPAD 68   // k6 LDS row stride (ushorts): 136B = 34 dwords -> 2-way (free)
#define LDSFENCE() asm volatile("s_waitcnt lgkmcnt(0)" ::: "memory")
#define LD8(P) (*reinterpret_cast<const short8*>(P))

// ---- ws layout (float offsets) ----
#define WS_TH     0        // [24][128] f32
#define WS_PV     3072     // [24][64]  f32
#define WS_PVSQ   4608     // [24] (pad 32)
#define WS_CTAB   4640     // [24][64]
#define WS_MID1   6176     // [64][64] f64 -> 8192 floats
#define WS_MID2   14368    // [64][64] f64
#define WS_BNSC   22560    // [64]
#define WS_BNSH   22624    // [64]
#define WS_WBF16  22688    // ushort region below
#define WO_FC1   0         // fc1w bf16 [64][64]
#define WO_GIH   4096      // gwih bf16 [192][64]
#define WO_GHH   16384     // gwhh bf16 [192][64]
#define WO_OUT   28672     // outw bf16 [16][64] (rows 12-15 zero)
#define WO_PV    29696     // pv bf16 [32][64] (rows 24-31 zero)
#define WO_CVX   31744     // convw[:, :64] bf16 [64][64]

__device__ __forceinline__ float sigf(float x){ return 1.0f/(1.0f+expf(-x)); }
__device__ __forceinline__ float fsig(float x){
  return __builtin_amdgcn_rcpf(1.f + __expf(-x));
}
__device__ __forceinline__ float ftanh(float x){
  return 1.f - 2.f*__builtin_amdgcn_rcpf(1.f + __expf(2.f*x));
}
__device__ __forceinline__ ushort_t f2bf(float f){
  unsigned u = __builtin_bit_cast(unsigned, f);
  u += 0x7FFFu + ((u>>16)&1u);           // round-to-nearest-even
  return (ushort_t)(u>>16);
}
__device__ __forceinline__ float bf2f(ushort_t b){
  return __builtin_bit_cast(float, ((unsigned)b)<<16);
}
// HW packed f32x2 -> bf16x2 (RNE), 1 VALU instr
__device__ __forceinline__ unsigned pk2bf(float a, float b){
  unsigned d;
  asm("v_cvt_pk_bf16_f32 %0, %1, %2" : "=v"(d) : "v"(a), "v"(b));
  return d;
}
// 1-instr scalar f32->bf16 (low half of cvt_pk)
__device__ __forceinline__ ushort_t f2bf_hw(float x){
  unsigned d;
  asm("v_cvt_pk_bf16_f32 %0, %1, %2" : "=v"(d) : "v"(x), "v"(x));
  return (ushort_t)d;
}

// ---------------- K1: biLSTM (blocks 0-23) + static weight->bf16 conv (blocks 24-27) ----------------
__global__ __launch_bounds__(256) void k1_lstm(
    const float* __restrict__ jq,
    const float* __restrict__ wif, const float* __restrict__ whf,
    const float* __restrict__ bif, const float* __restrict__ bhf,
    const float* __restrict__ wib, const float* __restrict__ bib, const float* __restrict__ bhb,
    const float* __restrict__ fc1w, const float* __restrict__ gwih,
    const float* __restrict__ gwhh, const float* __restrict__ outw,
    const float* __restrict__ convw, ushort_t* __restrict__ wb,
    float* __restrict__ th)
{
  __shared__ float hs[NHID];
  __shared__ float gs[4*NHID];
  if (blockIdx.x >= NPROTO){
    const int tt = (blockIdx.x - NPROTO)*256 + threadIdx.x;   // 0..1023
    for (int i=tt;i<4096;i+=1024)  wb[WO_FC1+i]=f2bf(fc1w[i]);
    for (int i=tt;i<12288;i+=1024){ wb[WO_GIH+i]=f2bf(gwih[i]); wb[WO_GHH+i]=f2bf(gwhh[i]); }
    for (int i=tt;i<1024;i+=1024)  wb[WO_OUT+i] = (i<768)? f2bf(outw[i]) : (ushort_t)0;
    for (int i=tt;i<4096;i+=1024)  wb[WO_CVX+i] = f2bf(convw[(i>>6)*128 + (i&63)]);
    return;
  }
  const int p = blockIdx.x;
  const int j = threadIdx.x;
  float wh[NHID];
  #pragma unroll
  for (int k=0;k<NHID;k++) wh[k] = whf[j*NHID+k];
  const float wi0=wif[j*3], wi1=wif[j*3+1], wi2=wif[j*3+2];
  const float bj = bif[j]+bhf[j];
  float c = 0.f;
  if (j < NHID) hs[j] = 0.f;
  __syncthreads();
  for (int t=0;t<TSEQ;t++){
    const float x0=jq[(p*TSEQ+t)*3], x1=jq[(p*TSEQ+t)*3+1], x2=jq[(p*TSEQ+t)*3+2];
    float g = wi0*x0+wi1*x1+wi2*x2+bj;
    #pragma unroll
    for (int k=0;k<NHID;k++) g += wh[k]*hs[k];
    __syncthreads();
    gs[j] = g;
    __syncthreads();
    if (j < NHID){
      const float gi=gs[j], gf=gs[NHID+j], gg=gs[2*NHID+j], go=gs[3*NHID+j];
      c = sigf(gf)*c + sigf(gi)*tanhf(gg);
      hs[j] = sigf(go)*tanhf(c);
    }
    __syncthreads();
  }
  if (j < NHID) th[p*2*NHID + j] = hs[j];
  const float x0=jq[(p*TSEQ+TSEQ-1)*3], x1=jq[(p*TSEQ+TSEQ-1)*3+1], x2=jq[(p*TSEQ+TSEQ-1)*3+2];
  const float gb = wib[j*3]*x0 + wib[j*3+1]*x1 + wib[j*3+2]*x2 + bib[j]+bhb[j];
  __syncthreads();
  gs[j] = gb;
  __syncthreads();
  if (j < NHID){
    const float gi=gs[j], gg=gs[2*NHID+j], go=gs[3*NHID+j];
    const float cb = sigf(gi)*tanhf(gg);
    th[p*2*NHID + NHID + j] = sigf(go)*tanhf(cb);
  }
}

// ---------------- K2: prototype vectors, pv^2, conv "chosen" table, pv->bf16 ----------------
__global__ __launch_bounds__(64) void k2_proto(
    const float* __restrict__ th, const float* __restrict__ fclw, const float* __restrict__ fclb,
    const float* __restrict__ projw, const float* __restrict__ convw, const float* __restrict__ convb,
    float* __restrict__ pv, float* __restrict__ pvsq, float* __restrict__ ctab,
    ushort_t* __restrict__ wb)
{
  const int p = blockIdx.x, h = threadIdx.x;
  __shared__ float thr[2*NHID], t1[NHID], pvr[NHID];
  thr[h]      = th[p*2*NHID+h];
  thr[NHID+h] = th[p*2*NHID+NHID+h];
  __syncthreads();
  float acc = fclb[h];
  for (int k=0;k<2*NHID;k++) acc += thr[k]*fclw[h*2*NHID+k];
  t1[h] = fmaxf(acc,0.f);
  __syncthreads();
  float pvh = 0.f;
  for (int k=0;k<NHID;k++) pvh += t1[k]*projw[h*NHID+k];
  pv[p*NHID+h]=pvh; pvr[h]=pvh;
  wb[WO_PV + p*64 + h] = f2bf(pvh);
  if (p==0){
    #pragma unroll
    for (int r=24;r<32;r++) wb[WO_PV + r*64 + h] = (ushort_t)0;
  }
  __syncthreads();
  float ct = convb[h];
  for (int k=0;k<NHID;k++) ct += pvr[k]*convw[h*2*NHID+NHID+k];
  ctab[p*NHID+h]=ct;
  if (h==0){ float s=0.f; for (int k=0;k<NHID;k++) s+=pvr[k]*pvr[k]; pvsq[p]=s; }
}

// ---------------- K3: MFMA distances+logits+argmax+conv + BN partials ----------------
// launch_bounds(256,8): force <=64 total regs -> 8 waves/SIMD residency.
__global__ __launch_bounds__(256, 8) void k3_mfma(
    const float* __restrict__ inp, const int* __restrict__ month,
    const float* __restrict__ pvsq, const float* __restrict__ ctab,
    const float* __restrict__ lastw, const ushort_t* __restrict__ wb,
    float* __restrict__ out_logits, float* __restrict__ out_md,
    ushort_t* __restrict__ xgb, float* __restrict__ part1, float* __restrict__ part2)
{
  __shared__ ushort_t xl[64*72];     // x rows bf16
  __shared__ float insql[64];        // fp32 row ||x||^2
  __shared__ float pal[64*26];       // prototype activations (wave-local use)

  const int t = threadIdx.x;
  const int w = t>>6, lane = t&63;
  const int l15 = lane&15, kg = lane>>4, ko = kg*8;
  const int gcol = w*16 + l15;
  const int rbase = w*16;
  const int rowA = rbase + l15;
  const size_t rowblk = (size_t)blockIdx.x*64;

  // ---- stage loads FIRST (oldest in vmcnt queue) ----
  const int sr = t>>2, scb = (t&3)*16;
  float4 xr[4];
  #pragma unroll
  for (int i=0;i<4;i++)
    xr[i] = *reinterpret_cast<const float4*>(inp + (rowblk + sr)*64 + scb + i*4);
  const int mo = month[blockIdx.x*4 + w];

  // ---- weight fragments (land under stage processing) ----
  const short8 pv0a = LD8(wb + WO_PV + l15*64 + ko);
  const short8 pv0b = LD8(wb + WO_PV + l15*64 + 32 + ko);
  const short8 pv1a = LD8(wb + WO_PV + (16+l15)*64 + ko);
  const short8 pv1b = LD8(wb + WO_PV + (16+l15)*64 + 32 + ko);
  const float pq0 = pvsq[l15];
  const float pq1 = (l15<8)? pvsq[16+l15] : 0.f;
  const int season = ((mo+10)%12)/3;

  // ---- stage x -> bf16 LDS + fp32 insq (wave-local rows) ----
  {
    float ss = 0.f;
    #pragma unroll
    for (int i=0;i<4;i++){
      const float4 xv = xr[i];
      ss += xv.x*xv.x + xv.y*xv.y + xv.z*xv.z + xv.w*xv.w;
      uint2 yy; yy.x = pk2bf(xv.x, xv.y); yy.y = pk2bf(xv.z, xv.w);
      *reinterpret_cast<uint2*>(&xl[sr*72 + scb + i*4]) = yy;
    }
    ss += __shfl_xor(ss,1,4);
    ss += __shfl_xor(ss,2,4);
    if ((t&3)==0) insql[sr] = ss;
  }
  LDSFENCE();

  const short8 ax0 = LD8(&xl[rowA*72+ko]);
  const short8 ax1 = LD8(&xl[rowA*72+32+ko]);

  // ---- distances: xp = X . PV^T (wave-row decomp) ----
  f32x4 d0={0.f,0.f,0.f,0.f}, d1=d0;
  d0 = MFMA(ax0, pv0a, d0);
  d0 = MFMA(ax1, pv0b, d0);
  d1 = MFMA(ax0, pv1a, d1);
  d1 = MFMA(ax1, pv1b, d1);
  {
    #pragma unroll
    for (int j=0;j<4;j++){
      const int rloc = rbase + kg*4 + j;
      const float iq = insql[rloc];
      const float md0 = iq + pq0 - 2.f*d0[j];
      out_md[(rowblk+rloc)*24 + l15] = md0;
      pal[rloc*26 + l15] = __logf(md0+1.f) - __logf(md0+EPS_P);
      const float md1 = iq + pq1 - 2.f*d1[j];
      const float pa1 = __logf(md1+1.f) - __logf(md1+EPS_P);
      if (l15<8){
        out_md[(rowblk+rloc)*24 + 16+l15] = md1;
        pal[rloc*26 + 16+l15] = pa1;
      }
    }
  }
  LDSFENCE();   // own pal rows committed

  // ---- logits (wave-local rows) ----
  {
    const int r2 = rbase + (lane>>2), c = lane&3;
    float lgv = 0.f;
    #pragma unroll
    for (int p=0;p<24;p++) lgv += pal[r2*26+p]*lastw[c*24+p];
    out_logits[(rowblk+r2)*4 + c] = lgv;
  }

  // ---- month argmax over 6 seasonal protos (in-register result) ----
  int qsw;
  {
    float simv = -3.4e38f;
    const int j6 = lane & 7;
    if (j6 < 6){
      simv = 0.f;
      const int sp = season*6 + j6;
      #pragma unroll
      for (int i=0;i<16;i++) simv += pal[(rbase+i)*26 + sp];
    }
    int bidx = j6;
    { const float ov=__shfl_xor(simv,1,8); const int oi=__shfl_xor(bidx,1,8);
      if (ov>simv || (ov==simv && oi<bidx)){ simv=ov; bidx=oi; } }
    { const float ov=__shfl_xor(simv,2,8); const int oi=__shfl_xor(bidx,2,8);
      if (ov>simv || (ov==simv && oi<bidx)){ simv=ov; bidx=oi; } }
    { const float ov=__shfl_xor(simv,4,8); const int oi=__shfl_xor(bidx,4,8);
      if (ov>simv || (ov==simv && oi<bidx)){ simv=ov; bidx=oi; } }
    qsw = season*6 + bidx;
  }

  // ---- conv weight frags (consumed after barrier; latency hides there) ----
  const short8 cw0  = LD8(wb + WO_CVX + gcol*64 + ko);
  const short8 cw1  = LD8(wb + WO_CVX + gcol*64 + 32 + ko);
  __syncthreads();   // all waves' xl visible for cross-wave conv

  // ---- conv: col-tile per wave, weights loop-invariant; bf16 block-local out ----
  ushort_t* xgblk = xgb + (size_t)blockIdx.x*8192;
  const float cg = ctab[qsw*64 + gcol];
  float s1=0.f, s2=0.f;
  #pragma unroll
  for (int rg=0; rg<4; rg++){
    const int ra = rg*16 + l15;
    const short8 bx0 = LD8(&xl[ra*72+ko]);
    const short8 bx1 = LD8(&xl[ra*72+32+ko]);
    f32x4 ac={0.f,0.f,0.f,0.f};
    ac = MFMA(bx0, cw0, ac);
    ac = MFMA(bx1, cw1, ac);
    #pragma unroll
    for (int j=0;j<4;j++){
      const int rloc = rg*16 + kg*4 + j;
      const float v = ac[j] + cg;
      xgblk[rloc*64 + gcol] = f2bf_hw(v);
      s1 += v; s2 += v*v;
    }
  }
  s1 += __shfl_xor(s1,16); s1 += __shfl_xor(s1,32);
  s2 += __shfl_xor(s2,16); s2 += __shfl_xor(s2,32);
  if (kg==0){
    part1[(size_t)blockIdx.x*64 + gcol] = s1;
    part2[(size_t)blockIdx.x*64 + gcol] = s2;
  }
}

// ---------------- K4b: partials [4096][64] -> mid [64][64] f64 ----------------
__global__ __launch_bounds__(64) void k4b_reduce(
    const float* __restrict__ part1, const float* __restrict__ part2,
    double* __restrict__ mid1, double* __restrict__ mid2)
{
  const int i = blockIdx.x, c = threadIdx.x;
  double s1=0.0, s2=0.0;
  for (int b=i*64; b<i*64+64; b++){
    s1 += (double)part1[b*64+c];
    s2 += (double)part2[b*64+c];
  }
  mid1[i*64+c]=s1; mid2[i*64+c]=s2;
}

// ---------------- K5: BN stats finalize ----------------
__global__ __launch_bounds__(64) void k5_finalize(
    const double* __restrict__ mid1, const double* __restrict__ mid2,
    const float* __restrict__ bng, const float* __restrict__ bnb,
    float* __restrict__ bnsc, float* __restrict__ bnsh)
{
  const int f = threadIdx.x;
  double s1=0.0, s2=0.0;
  for (int i=0;i<64;i++){ s1+=mid1[i*64+f]; s2+=mid2[i*64+f]; }
  const double mu = s1 / (double)NROWS;
  double var = s2/(double)NROWS - mu*mu;
  if (var < 0.0) var = 0.0;
  const float sc = bng[f] * (float)(1.0/sqrt(var + (double)EPS_BN));
  bnsc[f]=sc;
  bnsh[f]=bnb[f]-(float)mu*sc;
}

// ---------------- K6: MFMA  BN->fc1->LN->GRU->head ----------------
// launch_bounds(256,8): force <=64 total regs -> 8 waves/SIMD residency.
// LDS 17408B -> 8 blocks/CU fit. Head-weight loads moved post-GRU to cut
// live range; GRU bias pairs pre-summed (-2 regs).
__global__ __launch_bounds__(256, 8) void k6_mfma(
    const ushort_t* __restrict__ xgb, const float* __restrict__ hidden,
    const float* __restrict__ bnsc, const float* __restrict__ bnsh,
    const float* __restrict__ fc1b, const float* __restrict__ lng, const float* __restrict__ lnb,
    const float* __restrict__ gbih, const float* __restrict__ gbhh,
    const float* __restrict__ outb,
    const ushort_t* __restrict__ wb,
    float* __restrict__ out_a, float* __restrict__ out_h)
{
  __shared__ ushort_t ybuf[64*LPAD];   // y -> ttl -> hvl (phased reuse)
  __shared__ ushort_t hidl[64*LPAD];
  const int t = threadIdx.x;
  const int lane = t & 63, w = t >> 6;
  const int l15 = lane & 15, kg = lane >> 4;
  const int ko = kg*8;
  const int rbase = w*16;
  const int rowA = rbase + l15;
  const int sr = t>>2, scb = (t&3)*16;

  // ---- stage loads FIRST (oldest in vmcnt queue) ----
  const ushort_t* xgp = xgb + (size_t)blockIdx.x*8192 + sr*64 + scb;
  const us8 xv0 = *reinterpret_cast<const us8*>(xgp);
  const us8 xv1 = *reinterpret_cast<const us8*>(xgp+8);
  const size_t g = ((size_t)blockIdx.x*64 + sr)*64 + scb;
  float4 hv4[4];
  #pragma unroll
  for (int i=0;i<4;i++)
    hv4[i] = *reinterpret_cast<const float4*>(hidden + g + i*4);

  // ---- fc1 weight frags (land under stage processing) ----
  const short8 f0a = LD8(wb + WO_FC1 + ( 0+l15)*64 + ko);
  const short8 f0b = LD8(wb + WO_FC1 + ( 0+l15)*64 + 32 + ko);
  const short8 f1a = LD8(wb + WO_FC1 + (16+l15)*64 + ko);
  const short8 f1b = LD8(wb + WO_FC1 + (16+l15)*64 + 32 + ko);
  const short8 f2a = LD8(wb + WO_FC1 + (32+l15)*64 + ko);
  const short8 f2b = LD8(wb + WO_FC1 + (32+l15)*64 + 32 + ko);
  const short8 f3a = LD8(wb + WO_FC1 + (48+l15)*64 + ko);
  const short8 f3b = LD8(wb + WO_FC1 + (48+l15)*64 + 32 + ko);

  // ---- stage: BN+relu(x_bf16) and hidden -> bf16 LDS (wave-local rows) ----
  {
    float xf[16];
    #pragma unroll
    for (int e=0;e<8;e++){ xf[e]=bf2f(xv0[e]); xf[8+e]=bf2f(xv1[e]); }
    #pragma unroll
    for (int i=0;i<4;i++){
      const float4 sc = *reinterpret_cast<const float4*>(bnsc + scb + i*4);
      const float4 sh = *reinterpret_cast<const float4*>(bnsh + scb + i*4);
      const float y0 = fmaxf(xf[4*i  ]*sc.x+sh.x, 0.f);
      const float y1 = fmaxf(xf[4*i+1]*sc.y+sh.y, 0.f);
      const float y2 = fmaxf(xf[4*i+2]*sc.z+sh.z, 0.f);
      const float y3 = fmaxf(xf[4*i+3]*sc.w+sh.w, 0.f);
      uint2 yy; yy.x = pk2bf(y0,y1); yy.y = pk2bf(y2,y3);
      *reinterpret_cast<uint2*>(&ybuf[sr*LPAD + scb + i*4]) = yy;
      const float4 h4 = hv4[i];
      uint2 hh; hh.x = pk2bf(h4.x,h4.y); hh.y = pk2bf(h4.z,h4.w);
      *reinterpret_cast<uint2*>(&hidl[sr*LPAD + scb + i*4]) = hh;
    }
  }
  LDSFENCE();   // own stage rows committed (fc1 reads own rows only)

  const short8 ay0 = LD8(&ybuf[rowA*LPAD + ko]);
  const short8 ay1 = LD8(&ybuf[rowA*LPAD + 32 + ko]);

  // ---- fc1 (wave-row decomp, preloaded frags) ----
  f32x4 ac0={0.f,0.f,0.f,0.f}, ac1=ac0, ac2=ac0, ac3=ac0;
  ac0 = MFMA(ay0, f0a, ac0);  ac0 = MFMA(ay1, f0b, ac0);
  ac1 = MFMA(ay0, f1a, ac1);  ac1 = MFMA(ay1, f1b, ac1);
  ac2 = MFMA(ay0, f2a, ac2);  ac2 = MFMA(ay1, f2b, ac2);
  ac3 = MFMA(ay0, f3a, ac3);  ac3 = MFMA(ay1, f3b, ac3);
  {
    const float b0=fc1b[l15], b1=fc1b[16+l15], b2=fc1b[32+l15], b3=fc1b[48+l15];
    float tn0[4], tn1[4], tn2[4], tn3[4], mu[4], rs[4];
    #pragma unroll
    for (int j=0;j<4;j++){ tn0[j]=ac0[j]+b0; tn1[j]=ac1[j]+b1; tn2[j]=ac2[j]+b2; tn3[j]=ac3[j]+b3; }
    #pragma unroll
    for (int j=0;j<4;j++){
      float s = tn0[j]+tn1[j]+tn2[j]+tn3[j];
      s += __shfl_xor(s,1,16); s += __shfl_xor(s,2,16);
      s += __shfl_xor(s,4,16); s += __shfl_xor(s,8,16);
      mu[j] = s*(1.f/64.f);
    }
    #pragma unroll
    for (int j=0;j<4;j++){
      const float d0_=tn0[j]-mu[j], d1_=tn1[j]-mu[j], d2_=tn2[j]-mu[j], d3_=tn3[j]-mu[j];
      float v = d0_*d0_+d1_*d1_+d2_*d2_+d3_*d3_;
      v += __shfl_xor(v,1,16); v += __shfl_xor(v,2,16);
      v += __shfl_xor(v,4,16); v += __shfl_xor(v,8,16);
      rs[j] = 1.f/sqrtf(v*(1.f/64.f)+EPS_LN);
    }
    const float g0=lng[l15], g1=lng[16+l15], g2=lng[32+l15], g3=lng[48+l15];
    const float q0=lnb[l15], q1=lnb[16+l15], q2=lnb[32+l15], q3=lnb[48+l15];
    // LN into own stripe; antidep vs own ay reads is program order.
    #pragma unroll
    for (int j=0;j<4;j++){
      const int rr_ = rbase + kg*4 + j;
      ybuf[rr_*LPAD +      l15] = f2bf_hw(fmaxf((tn0[j]-mu[j])*rs[j]*g0+q0, 0.f));
      ybuf[rr_*LPAD + 16 + l15] = f2bf_hw(fmaxf((tn1[j]-mu[j])*rs[j]*g1+q1, 0.f));
      ybuf[rr_*LPAD + 32 + l15] = f2bf_hw(fmaxf((tn2[j]-mu[j])*rs[j]*g2+q2, 0.f));
      ybuf[rr_*LPAD + 48 + l15] = f2bf_hw(fmaxf((tn3[j]-mu[j])*rs[j]*g3+q3, 0.f));
    }
  }

  // ---- prefetch GRU (col gcol) weight frags + biases; land during barrier ----
  const int gcol = w*16 + l15;
  const ushort_t* gih = wb + WO_GIH;
  const ushort_t* ghh = wb + WO_GHH;
  const short8 wr0 = LD8(gih + (      gcol)*64 + ko);
  const short8 wr1 = LD8(gih + (      gcol)*64 + 32 + ko);
  const short8 wz0 = LD8(gih + ( 64 + gcol)*64 + ko);
  const short8 wz1 = LD8(gih + ( 64 + gcol)*64 + 32 + ko);
  const short8 wn0 = LD8(gih + (128 + gcol)*64 + ko);
  const short8 wn1 = LD8(gih + (128 + gcol)*64 + 32 + ko);
  const short8 vr0 = LD8(ghh + (      gcol)*64 + ko);
  const short8 vr1 = LD8(ghh + (      gcol)*64 + 32 + ko);
  const short8 vz0 = LD8(ghh + ( 64 + gcol)*64 + ko);
  const short8 vz1 = LD8(ghh + ( 64 + gcol)*64 + 32 + ko);
  const short8 vn0 = LD8(ghh + (128 + gcol)*64 + ko);
  const short8 vn1 = LD8(ghh + (128 + gcol)*64 + 32 + ko);
  const float br  = gbih[gcol]     + gbhh[gcol];
  const float bz  = gbih[64+gcol]  + gbhh[64+gcol];
  const float bin_= gbih[128+gcol];
  const float bhn = gbhh[128+gcol];
  __syncthreads();   // ttl + all waves' stage visible

  // ---- GRU: col-tile per wave, 4 row-groups; keep h bf16 in regs ----
  us4 hkeep[4];
  #pragma unroll
  for (int rg=0; rg<4; rg++){
    const int ra = rg*16 + l15;
    const short8 at0 = LD8(&ybuf[ra*LPAD + ko]);
    const short8 at1 = LD8(&ybuf[ra*LPAD + 32 + ko]);
    const short8 bh0 = LD8(&hidl[ra*LPAD + ko]);
    const short8 bh1 = LD8(&hidl[ra*LPAD + 32 + ko]);
    f32x4 ar={0.f,0.f,0.f,0.f}, az=ar, an=ar, hn=ar;
    ar = MFMA(at0, wr0, ar);  ar = MFMA(at1, wr1, ar);
    ar = MFMA(bh0, vr0, ar);  ar = MFMA(bh1, vr1, ar);
    az = MFMA(at0, wz0, az);  az = MFMA(at1, wz1, az);
    az = MFMA(bh0, vz0, az);  az = MFMA(bh1, vz1, az);
    an = MFMA(at0, wn0, an);  an = MFMA(at1, wn1, an);
    hn = MFMA(bh0, vn0, hn);  hn = MFMA(bh1, vn1, hn);
    us4 hb4;
    #pragma unroll
    for (int j=0;j<4;j++){
      const int rloc = rg*16 + kg*4 + j;
      const size_t rg_ = (size_t)blockIdx.x*64 + rloc;
      const float rrg = fsig(ar[j]+br);
      const float zzg = fsig(az[j]+bz);
      const float nng = ftanh(an[j]+bin_ + rrg*(hn[j]+bhn));
      const float hold = bf2f(hidl[rloc*LPAD + gcol]);
      const float hv = (1.f-zzg)*nng + zzg*hold;
      out_h[rg_*64 + gcol] = hv;
      hb4[j] = f2bf_hw(hv);
    }
    hkeep[rg] = hb4;
  }

  __syncthreads();   // all waves done reading ttl/hidl -> ybuf reusable as hvl

  // ---- head weight frags + bias (latency hides under scatter + barrier) ----
  const short8 ow0 = LD8(wb + WO_OUT + l15*64 + ko);
  const short8 ow1 = LD8(wb + WO_OUT + l15*64 + 32 + ko);
  const float ob = (l15 < 12) ? outb[l15] : 0.f;

  #pragma unroll
  for (int rg=0; rg<4; rg++){
    #pragma unroll
    for (int j=0;j<4;j++)
      ybuf[(rg*16 + kg*4 + j)*LPAD + gcol] = hkeep[rg][j];
  }
  __syncthreads();   // hvl ready

  // ---- output head (wave-row decomp) ----
  const short8 av0 = LD8(&ybuf[rowA*LPAD + ko]);
  const short8 av1 = LD8(&ybuf[rowA*LPAD + 32 + ko]);
  f32x4 aa={0.f,0.f,0.f,0.f};
  aa = MFMA(av0, ow0, aa);
  aa = MFMA(av1, ow1, aa);
  if (l15 < 12){
    #pragma unroll
    for (int j=0;j<4;j++){
      const size_t rg_ = (size_t)blockIdx.x*64 + rbase + kg*4 + j;
      out_a[rg_*12 + l15] = aa[j] + ob;
    }
  }
}

extern "C" void kernel_launch(void* const* d_in, const int* in_sizes, int n_in,
                              void* d_out, int out_size, void* d_ws, size_t ws_size,
                              hipStream_t stream)
{
  (void)in_sizes; (void)n_in; (void)out_size; (void)ws_size;
  const float* inputs = (const float*)d_in[0];
  const float* hidden = (const float*)d_in[1];
  const int*   month  = (const int*)d_in[2];
  const float* jq     = (const float*)d_in[3];
  const float* wif    = (const float*)d_in[4];
  const float* whf    = (const float*)d_in[5];
  const float* bif    = (const float*)d_in[6];
  const float* bhf    = (const float*)d_in[7];
  const float* wib    = (const float*)d_in[8];
  const float* bib    = (const float*)d_in[10];
  const float* bhb    = (const float*)d_in[11];
  const float* fclw   = (const float*)d_in[12];
  const float* fclb   = (const float*)d_in[13];
  const float* projw  = (const float*)d_in[14];
  const float* convw  = (const float*)d_in[15];
  const float* convb  = (const float*)d_in[16];
  const float* bng    = (const float*)d_in[17];
  const float* bnb    = (const float*)d_in[18];
  const float* fc1w   = (const float*)d_in[19];
  const float* fc1b   = (const float*)d_in[20];
  const float* lng    = (const float*)d_in[21];
  const float* lnb    = (const float*)d_in[22];
  const float* gwih   = (const float*)d_in[23];
  const float* gwhh   = (const float*)d_in[24];
  const float* gbih   = (const float*)d_in[25];
  const float* gbhh   = (const float*)d_in[26];
  const float* outw   = (const float*)d_in[27];
  const float* outb   = (const float*)d_in[28];
  const float* lastw  = (const float*)d_in[29];

  float* ws  = (float*)d_ws;
  float* out = (float*)d_out;
  float* out_a  = out;
  float* out_h  = out + (size_t)NROWS*NACT;
  float* out_lg = out + (size_t)NROWS*(NACT+NHID);
  float* out_md = out + (size_t)NROWS*(NACT+NHID+4);
  ushort_t* wb = (ushort_t*)(ws + WS_WBF16);
  ushort_t* xgb = (ushort_t*)out_h;     // bf16 x_glb, block-local packed
  float* part1 = out_a;                 // [4096][64]
  float* part2 = out_a + (size_t)4096*64;

  hipLaunchKernelGGL(k1_lstm, dim3(NPROTO+4), dim3(256), 0, stream,
                     jq, wif, whf, bif, bhf, wib, bib, bhb,
                     fc1w, gwih, gwhh, outw, convw, wb, ws+WS_TH);
  hipLaunchKernelGGL(k2_proto, dim3(NPROTO), dim3(64), 0, stream,
                     ws+WS_TH, fclw, fclb, projw, convw, convb,
                     ws+WS_PV, ws+WS_PVSQ, ws+WS_CTAB, wb);
  hipLaunchKernelGGL(k3_mfma, dim3(NROWS/64), dim3(256), 0, stream,
                     inputs, month, ws+WS_PVSQ, ws+WS_CTAB, lastw, wb,
                     out_lg, out_md, xgb, part1, part2);
  hipLaunchKernelGGL(k4b_reduce, dim3(64), dim3(64), 0, stream,
                     part1, part2, (double*)(ws+WS_MID1), (double*)(ws+WS_MID2));
  hipLaunchKernelGGL(k5_finalize, dim3(1), dim3(64), 0, stream,
                     (const double*)(ws+WS_MID1), (const double*)(ws+WS_MID2),
                     bng, bnb, ws+WS_BNSC, ws+WS_BNSH);
  hipLaunchKernelGGL(k6_mfma, dim3(NROWS/64), dim3(256), 0, stream,
                     xgb, hidden, ws+WS_BNSC, ws+WS_BNSH, fc1b, lng, lnb,
                     gbih, gbhh, outb, wb, out_a, out_h);
}

// Round 7
// 149.510 us; speedup vs baseline: 1.9415x; 1.9415x over previous
//
#include <hip/hip_runtime.h>
#include <cmath>

#define NHID 64
#define NMONTH 16384
#define NAGENT 16
#define NROWS (NMONTH*NAGENT)   // 262144
#define NPROTO 24
#define TSEQ 32
#define NACT 12
#define EPS_P  1e-4f
#define EPS_BN 1e-5f
#define EPS_LN 1e-5f

typedef __attribute__((ext_vector_type(8))) short short8;
typedef __attribute__((ext_vector_type(4))) float f32x4;
typedef __attribute__((ext_vector_type(4))) unsigned short us4;
typedef __attribute__((ext_vector_type(8))) unsigned short us8;
typedef unsigned short ushort_t;

#define MFMA(a,b,c) __builtin_amdgcn_mfma_f32_16x16x32_bf16(a,b,c,0,0,0)
#define LPAD 68   // k6 LDS row stride (ushorts): 136B = 34 dwords -> 2-way (free)
#define LDSFENCE() asm volatile("s_waitcnt lgkmcnt(0)" ::: "memory")
#define LD8(P) (*reinterpret_cast<const short8*>(P))

// ---- ws layout (float offsets) ----
#define WS_TH     0        // [24][128] f32
#define WS_PV     3072     // [24][64]  f32
#define WS_PVSQ   4608     // [24] (pad 32)
#define WS_CTAB   4640     // [24][64]
#define WS_MID1   6176     // [64][64] f64 -> 8192 floats
#define WS_MID2   14368    // [64][64] f64
#define WS_BNSC   22560    // [64]
#define WS_BNSH   22624    // [64]
#define WS_WBF16  22688    // ushort region below
#define WO_FC1   0         // fc1w bf16 [64][64]
#define WO_GIH   4096      // gwih bf16 [192][64]
#define WO_GHH   16384     // gwhh bf16 [192][64]
#define WO_OUT   28672     // outw bf16 [16][64] (rows 12-15 zero)
#define WO_PV    29696     // pv bf16 [32][64] (rows 24-31 zero)
#define WO_CVX   31744     // convw[:, :64] bf16 [64][64]

__device__ __forceinline__ float sigf(float x){ return 1.0f/(1.0f+expf(-x)); }
__device__ __forceinline__ float fsig(float x){
  return __builtin_amdgcn_rcpf(1.f + __expf(-x));
}
__device__ __forceinline__ float ftanh(float x){
  return 1.f - 2.f*__builtin_amdgcn_rcpf(1.f + __expf(2.f*x));
}
__device__ __forceinline__ ushort_t f2bf(float f){
  unsigned u = __builtin_bit_cast(unsigned, f);
  u += 0x7FFFu + ((u>>16)&1u);           // round-to-nearest-even
  return (ushort_t)(u>>16);
}
__device__ __forceinline__ float bf2f(ushort_t b){
  return __builtin_bit_cast(float, ((unsigned)b)<<16);
}
// HW packed f32x2 -> bf16x2 (RNE), 1 VALU instr
__device__ __forceinline__ unsigned pk2bf(float a, float b){
  unsigned d;
  asm("v_cvt_pk_bf16_f32 %0, %1, %2" : "=v"(d) : "v"(a), "v"(b));
  return d;
}
// 1-instr scalar f32->bf16 (low half of cvt_pk)
__device__ __forceinline__ ushort_t f2bf_hw(float x){
  unsigned d;
  asm("v_cvt_pk_bf16_f32 %0, %1, %2" : "=v"(d) : "v"(x), "v"(x));
  return (ushort_t)d;
}

// ---------------- K1: biLSTM (blocks 0-23) + static weight->bf16 conv (blocks 24-27) ----------------
__global__ __launch_bounds__(256) void k1_lstm(
    const float* __restrict__ jq,
    const float* __restrict__ wif, const float* __restrict__ whf,
    const float* __restrict__ bif, const float* __restrict__ bhf,
    const float* __restrict__ wib, const float* __restrict__ bib, const float* __restrict__ bhb,
    const float* __restrict__ fc1w, const float* __restrict__ gwih,
    const float* __restrict__ gwhh, const float* __restrict__ outw,
    const float* __restrict__ convw, ushort_t* __restrict__ wb,
    float* __restrict__ th)
{
  __shared__ float hs[NHID];
  __shared__ float gs[4*NHID];
  if (blockIdx.x >= NPROTO){
    const int tt = (blockIdx.x - NPROTO)*256 + threadIdx.x;   // 0..1023
    for (int i=tt;i<4096;i+=1024)  wb[WO_FC1+i]=f2bf(fc1w[i]);
    for (int i=tt;i<12288;i+=1024){ wb[WO_GIH+i]=f2bf(gwih[i]); wb[WO_GHH+i]=f2bf(gwhh[i]); }
    for (int i=tt;i<1024;i+=1024)  wb[WO_OUT+i] = (i<768)? f2bf(outw[i]) : (ushort_t)0;
    for (int i=tt;i<4096;i+=1024)  wb[WO_CVX+i] = f2bf(convw[(i>>6)*128 + (i&63)]);
    return;
  }
  const int p = blockIdx.x;
  const int j = threadIdx.x;
  float wh[NHID];
  #pragma unroll
  for (int k=0;k<NHID;k++) wh[k] = whf[j*NHID+k];
  const float wi0=wif[j*3], wi1=wif[j*3+1], wi2=wif[j*3+2];
  const float bj = bif[j]+bhf[j];
  float c = 0.f;
  if (j < NHID) hs[j] = 0.f;
  __syncthreads();
  for (int t=0;t<TSEQ;t++){
    const float x0=jq[(p*TSEQ+t)*3], x1=jq[(p*TSEQ+t)*3+1], x2=jq[(p*TSEQ+t)*3+2];
    float g = wi0*x0+wi1*x1+wi2*x2+bj;
    #pragma unroll
    for (int k=0;k<NHID;k++) g += wh[k]*hs[k];
    __syncthreads();
    gs[j] = g;
    __syncthreads();
    if (j < NHID){
      const float gi=gs[j], gf=gs[NHID+j], gg=gs[2*NHID+j], go=gs[3*NHID+j];
      c = sigf(gf)*c + sigf(gi)*tanhf(gg);
      hs[j] = sigf(go)*tanhf(c);
    }
    __syncthreads();
  }
  if (j < NHID) th[p*2*NHID + j] = hs[j];
  const float x0=jq[(p*TSEQ+TSEQ-1)*3], x1=jq[(p*TSEQ+TSEQ-1)*3+1], x2=jq[(p*TSEQ+TSEQ-1)*3+2];
  const float gb = wib[j*3]*x0 + wib[j*3+1]*x1 + wib[j*3+2]*x2 + bib[j]+bhb[j];
  __syncthreads();
  gs[j] = gb;
  __syncthreads();
  if (j < NHID){
    const float gi=gs[j], gg=gs[2*NHID+j], go=gs[3*NHID+j];
    const float cb = sigf(gi)*tanhf(gg);
    th[p*2*NHID + NHID + j] = sigf(go)*tanhf(cb);
  }
}

// ---------------- K2: prototype vectors, pv^2, conv "chosen" table, pv->bf16 ----------------
__global__ __launch_bounds__(64) void k2_proto(
    const float* __restrict__ th, const float* __restrict__ fclw, const float* __restrict__ fclb,
    const float* __restrict__ projw, const float* __restrict__ convw, const float* __restrict__ convb,
    float* __restrict__ pv, float* __restrict__ pvsq, float* __restrict__ ctab,
    ushort_t* __restrict__ wb)
{
  const int p = blockIdx.x, h = threadIdx.x;
  __shared__ float thr[2*NHID], t1[NHID], pvr[NHID];
  thr[h]      = th[p*2*NHID+h];
  thr[NHID+h] = th[p*2*NHID+NHID+h];
  __syncthreads();
  float acc = fclb[h];
  for (int k=0;k<2*NHID;k++) acc += thr[k]*fclw[h*2*NHID+k];
  t1[h] = fmaxf(acc,0.f);
  __syncthreads();
  float pvh = 0.f;
  for (int k=0;k<NHID;k++) pvh += t1[k]*projw[h*NHID+k];
  pv[p*NHID+h]=pvh; pvr[h]=pvh;
  wb[WO_PV + p*64 + h] = f2bf(pvh);
  if (p==0){
    #pragma unroll
    for (int r=24;r<32;r++) wb[WO_PV + r*64 + h] = (ushort_t)0;
  }
  __syncthreads();
  float ct = convb[h];
  for (int k=0;k<NHID;k++) ct += pvr[k]*convw[h*2*NHID+NHID+k];
  ctab[p*NHID+h]=ct;
  if (h==0){ float s=0.f; for (int k=0;k<NHID;k++) s+=pvr[k]*pvr[k]; pvsq[p]=s; }
}

// ---------------- K3: MFMA distances+logits+argmax+conv + BN partials ----------------
// md staged in LDS, written back linearly (coalesced). One barrier (pre-conv).
__global__ __launch_bounds__(256) void k3_mfma(
    const float* __restrict__ inp, const int* __restrict__ month,
    const float* __restrict__ pvsq, const float* __restrict__ ctab,
    const float* __restrict__ lastw, const ushort_t* __restrict__ wb,
    float* __restrict__ out_logits, float* __restrict__ out_md,
    ushort_t* __restrict__ xgb, float* __restrict__ part1, float* __restrict__ part2)
{
  __shared__ ushort_t xl[64*72];     // x rows bf16
  __shared__ float insql[64];        // fp32 row ||x||^2
  __shared__ float pal[64*26];       // prototype activations (wave-local use)
  __shared__ float mdl[64*25];       // raw min_distances (row*25+col)

  const int t = threadIdx.x;
  const int w = t>>6, lane = t&63;
  const int l15 = lane&15, kg = lane>>4, ko = kg*8;
  const int gcol = w*16 + l15;
  const int rbase = w*16;
  const int rowA = rbase + l15;
  const size_t rowblk = (size_t)blockIdx.x*64;

  // ---- stage loads FIRST (oldest in vmcnt queue) ----
  const int sr = t>>2, scb = (t&3)*16;
  float4 xr[4];
  #pragma unroll
  for (int i=0;i<4;i++)
    xr[i] = *reinterpret_cast<const float4*>(inp + (rowblk + sr)*64 + scb + i*4);
  const int mo = month[blockIdx.x*4 + w];

  // ---- weight fragments (land under stage processing) ----
  const short8 pv0a = LD8(wb + WO_PV + l15*64 + ko);
  const short8 pv0b = LD8(wb + WO_PV + l15*64 + 32 + ko);
  const short8 pv1a = LD8(wb + WO_PV + (16+l15)*64 + ko);
  const short8 pv1b = LD8(wb + WO_PV + (16+l15)*64 + 32 + ko);
  const float pq0 = pvsq[l15];
  const float pq1 = (l15<8)? pvsq[16+l15] : 0.f;
  const int season = ((mo+10)%12)/3;

  // ---- stage x -> bf16 LDS + fp32 insq (wave-local rows) ----
  {
    float ss = 0.f;
    #pragma unroll
    for (int i=0;i<4;i++){
      const float4 xv = xr[i];
      ss += xv.x*xv.x + xv.y*xv.y + xv.z*xv.z + xv.w*xv.w;
      uint2 yy; yy.x = pk2bf(xv.x, xv.y); yy.y = pk2bf(xv.z, xv.w);
      *reinterpret_cast<uint2*>(&xl[sr*72 + scb + i*4]) = yy;
    }
    ss += __shfl_xor(ss,1,4);
    ss += __shfl_xor(ss,2,4);
    if ((t&3)==0) insql[sr] = ss;
  }
  LDSFENCE();

  const short8 ax0 = LD8(&xl[rowA*72+ko]);
  const short8 ax1 = LD8(&xl[rowA*72+32+ko]);

  // ---- distances: xp = X . PV^T (wave-row decomp) ----
  f32x4 d0={0.f,0.f,0.f,0.f}, d1=d0;
  d0 = MFMA(ax0, pv0a, d0);
  d0 = MFMA(ax1, pv0b, d0);
  d1 = MFMA(ax0, pv1a, d1);
  d1 = MFMA(ax1, pv1b, d1);
  {
    #pragma unroll
    for (int j=0;j<4;j++){
      const int rloc = rbase + kg*4 + j;
      const float iq = insql[rloc];
      const float md0 = iq + pq0 - 2.f*d0[j];
      mdl[rloc*25 + l15] = md0;
      pal[rloc*26 + l15] = __logf(md0+1.f) - __logf(md0+EPS_P);
      const float md1 = iq + pq1 - 2.f*d1[j];
      const float pa1 = __logf(md1+1.f) - __logf(md1+EPS_P);
      if (l15<8){
        mdl[rloc*25 + 16+l15] = md1;
        pal[rloc*26 + 16+l15] = pa1;
      }
    }
  }
  LDSFENCE();   // own pal/mdl rows committed

  // ---- logits (wave-local rows) ----
  {
    const int r2 = rbase + (lane>>2), c = lane&3;
    float lgv = 0.f;
    #pragma unroll
    for (int p=0;p<24;p++) lgv += pal[r2*26+p]*lastw[c*24+p];
    out_logits[(rowblk+r2)*4 + c] = lgv;
  }

  // ---- month argmax over 6 seasonal protos (in-register result) ----
  int qsw;
  {
    float simv = -3.4e38f;
    const int j6 = lane & 7;
    if (j6 < 6){
      simv = 0.f;
      const int sp = season*6 + j6;
      #pragma unroll
      for (int i=0;i<16;i++) simv += pal[(rbase+i)*26 + sp];
    }
    int bidx = j6;
    { const float ov=__shfl_xor(simv,1,8); const int oi=__shfl_xor(bidx,1,8);
      if (ov>simv || (ov==simv && oi<bidx)){ simv=ov; bidx=oi; } }
    { const float ov=__shfl_xor(simv,2,8); const int oi=__shfl_xor(bidx,2,8);
      if (ov>simv || (ov==simv && oi<bidx)){ simv=ov; bidx=oi; } }
    { const float ov=__shfl_xor(simv,4,8); const int oi=__shfl_xor(bidx,4,8);
      if (ov>simv || (ov==simv && oi<bidx)){ simv=ov; bidx=oi; } }
    qsw = season*6 + bidx;
  }

  // ---- conv weight frags (consumed after barrier; latency hides there) ----
  const short8 cw0  = LD8(wb + WO_CVX + gcol*64 + ko);
  const short8 cw1  = LD8(wb + WO_CVX + gcol*64 + 32 + ko);
  __syncthreads();   // all waves' xl + mdl visible

  // ---- conv: col-tile per wave, weights loop-invariant; bf16 block-local out ----
  ushort_t* xgblk = xgb + (size_t)blockIdx.x*8192;
  const float cg = ctab[qsw*64 + gcol];
  float s1=0.f, s2=0.f;
  #pragma unroll
  for (int rg=0; rg<4; rg++){
    const int ra = rg*16 + l15;
    const short8 bx0 = LD8(&xl[ra*72+ko]);
    const short8 bx1 = LD8(&xl[ra*72+32+ko]);
    f32x4 ac={0.f,0.f,0.f,0.f};
    ac = MFMA(bx0, cw0, ac);
    ac = MFMA(bx1, cw1, ac);
    #pragma unroll
    for (int j=0;j<4;j++){
      const int rloc = rg*16 + kg*4 + j;
      const float v = ac[j] + cg;
      xgblk[rloc*64 + gcol] = f2bf_hw(v);
      s1 += v; s2 += v*v;
    }
  }
  s1 += __shfl_xor(s1,16); s1 += __shfl_xor(s1,32);
  s2 += __shfl_xor(s2,16); s2 += __shfl_xor(s2,32);
  if (kg==0){
    part1[(size_t)blockIdx.x*64 + gcol] = s1;
    part2[(size_t)blockIdx.x*64 + gcol] = s2;
  }

  // ---- out_md coalesced writeback: 1536 dwords, 6 per thread ----
  {
    float* omd = out_md + (size_t)blockIdx.x*1536;
    #pragma unroll
    for (int k=0;k<6;k++){
      const int idx = t + k*256;
      const int row = (idx*2731)>>16;      // idx/24 for idx<1536
      const int col = idx - row*24;
      omd[idx] = mdl[row*25 + col];
    }
  }
}

// ---------------- K4b: partials [4096][64] -> mid [64][64] f64 ----------------
__global__ __launch_bounds__(64) void k4b_reduce(
    const float* __restrict__ part1, const float* __restrict__ part2,
    double* __restrict__ mid1, double* __restrict__ mid2)
{
  const int i = blockIdx.x, c = threadIdx.x;
  double s1=0.0, s2=0.0;
  for (int b=i*64; b<i*64+64; b++){
    s1 += (double)part1[b*64+c];
    s2 += (double)part2[b*64+c];
  }
  mid1[i*64+c]=s1; mid2[i*64+c]=s2;
}

// ---------------- K5: BN stats finalize ----------------
__global__ __launch_bounds__(64) void k5_finalize(
    const double* __restrict__ mid1, const double* __restrict__ mid2,
    const float* __restrict__ bng, const float* __restrict__ bnb,
    float* __restrict__ bnsc, float* __restrict__ bnsh)
{
  const int f = threadIdx.x;
  double s1=0.0, s2=0.0;
  for (int i=0;i<64;i++){ s1+=mid1[i*64+f]; s2+=mid2[i*64+f]; }
  const double mu = s1 / (double)NROWS;
  double var = s2/(double)NROWS - mu*mu;
  if (var < 0.0) var = 0.0;
  const float sc = bng[f] * (float)(1.0/sqrt(var + (double)EPS_BN));
  bnsc[f]=sc;
  bnsh[f]=bnb[f]-(float)mu*sc;
}

// ---------------- K6: MFMA  BN->fc1->LN->GRU->head ----------------
// out_h no longer stored in the GRU loop: h (bf16) goes to LDS (hvl scatter,
// needed for the head anyway) and is written back fully coalesced (dwordx4)
// after the hvl barrier. Removes 16 scattered scalar stores/lane from the
// pre-barrier vmcnt drain.
__global__ __launch_bounds__(256) void k6_mfma(
    const ushort_t* __restrict__ xgb, const float* __restrict__ hidden,
    const float* __restrict__ bnsc, const float* __restrict__ bnsh,
    const float* __restrict__ fc1b, const float* __restrict__ lng, const float* __restrict__ lnb,
    const float* __restrict__ gbih, const float* __restrict__ gbhh,
    const float* __restrict__ outb,
    const ushort_t* __restrict__ wb,
    float* __restrict__ out_a, float* __restrict__ out_h)
{
  __shared__ ushort_t ybuf[64*LPAD];   // y -> ttl -> hvl (phased reuse)
  __shared__ ushort_t hidl[64*LPAD];
  const int t = threadIdx.x;
  const int lane = t & 63, w = t >> 6;
  const int l15 = lane & 15, kg = lane >> 4;
  const int ko = kg*8;
  const int rbase = w*16;
  const int rowA = rbase + l15;
  const int sr = t>>2, scb = (t&3)*16;

  // ---- stage loads FIRST (oldest in vmcnt queue) ----
  const ushort_t* xgp = xgb + (size_t)blockIdx.x*8192 + sr*64 + scb;
  const us8 xv0 = *reinterpret_cast<const us8*>(xgp);
  const us8 xv1 = *reinterpret_cast<const us8*>(xgp+8);
  const size_t g = ((size_t)blockIdx.x*64 + sr)*64 + scb;
  float4 hv4[4];
  #pragma unroll
  for (int i=0;i<4;i++)
    hv4[i] = *reinterpret_cast<const float4*>(hidden + g + i*4);

  // ---- fc1 weight frags (land under stage processing) ----
  const short8 f0a = LD8(wb + WO_FC1 + ( 0+l15)*64 + ko);
  const short8 f0b = LD8(wb + WO_FC1 + ( 0+l15)*64 + 32 + ko);
  const short8 f1a = LD8(wb + WO_FC1 + (16+l15)*64 + ko);
  const short8 f1b = LD8(wb + WO_FC1 + (16+l15)*64 + 32 + ko);
  const short8 f2a = LD8(wb + WO_FC1 + (32+l15)*64 + ko);
  const short8 f2b = LD8(wb + WO_FC1 + (32+l15)*64 + 32 + ko);
  const short8 f3a = LD8(wb + WO_FC1 + (48+l15)*64 + ko);
  const short8 f3b = LD8(wb + WO_FC1 + (48+l15)*64 + 32 + ko);

  // ---- stage: BN+relu(x_bf16) and hidden -> bf16 LDS (wave-local rows) ----
  {
    float xf[16];
    #pragma unroll
    for (int e=0;e<8;e++){ xf[e]=bf2f(xv0[e]); xf[8+e]=bf2f(xv1[e]); }
    #pragma unroll
    for (int i=0;i<4;i++){
      const float4 sc = *reinterpret_cast<const float4*>(bnsc + scb + i*4);
      const float4 sh = *reinterpret_cast<const float4*>(bnsh + scb + i*4);
      const float y0 = fmaxf(xf[4*i  ]*sc.x+sh.x, 0.f);
      const float y1 = fmaxf(xf[4*i+1]*sc.y+sh.y, 0.f);
      const float y2 = fmaxf(xf[4*i+2]*sc.z+sh.z, 0.f);
      const float y3 = fmaxf(xf[4*i+3]*sc.w+sh.w, 0.f);
      uint2 yy; yy.x = pk2bf(y0,y1); yy.y = pk2bf(y2,y3);
      *reinterpret_cast<uint2*>(&ybuf[sr*LPAD + scb + i*4]) = yy;
      const float4 h4 = hv4[i];
      uint2 hh; hh.x = pk2bf(h4.x,h4.y); hh.y = pk2bf(h4.z,h4.w);
      *reinterpret_cast<uint2*>(&hidl[sr*LPAD + scb + i*4]) = hh;
    }
  }
  LDSFENCE();   // own stage rows committed (fc1 reads own rows only)

  const short8 ay0 = LD8(&ybuf[rowA*LPAD + ko]);
  const short8 ay1 = LD8(&ybuf[rowA*LPAD + 32 + ko]);

  // ---- fc1 (wave-row decomp, preloaded frags) ----
  f32x4 ac0={0.f,0.f,0.f,0.f}, ac1=ac0, ac2=ac0, ac3=ac0;
  ac0 = MFMA(ay0, f0a, ac0);  ac0 = MFMA(ay1, f0b, ac0);
  ac1 = MFMA(ay0, f1a, ac1);  ac1 = MFMA(ay1, f1b, ac1);
  ac2 = MFMA(ay0, f2a, ac2);  ac2 = MFMA(ay1, f2b, ac2);
  ac3 = MFMA(ay0, f3a, ac3);  ac3 = MFMA(ay1, f3b, ac3);
  {
    const float b0=fc1b[l15], b1=fc1b[16+l15], b2=fc1b[32+l15], b3=fc1b[48+l15];
    float tn0[4], tn1[4], tn2[4], tn3[4], mu[4], rs[4];
    #pragma unroll
    for (int j=0;j<4;j++){ tn0[j]=ac0[j]+b0; tn1[j]=ac1[j]+b1; tn2[j]=ac2[j]+b2; tn3[j]=ac3[j]+b3; }
    #pragma unroll
    for (int j=0;j<4;j++){
      float s = tn0[j]+tn1[j]+tn2[j]+tn3[j];
      s += __shfl_xor(s,1,16); s += __shfl_xor(s,2,16);
      s += __shfl_xor(s,4,16); s += __shfl_xor(s,8,16);
      mu[j] = s*(1.f/64.f);
    }
    #pragma unroll
    for (int j=0;j<4;j++){
      const float d0_=tn0[j]-mu[j], d1_=tn1[j]-mu[j], d2_=tn2[j]-mu[j], d3_=tn3[j]-mu[j];
      float v = d0_*d0_+d1_*d1_+d2_*d2_+d3_*d3_;
      v += __shfl_xor(v,1,16); v += __shfl_xor(v,2,16);
      v += __shfl_xor(v,4,16); v += __shfl_xor(v,8,16);
      rs[j] = 1.f/sqrtf(v*(1.f/64.f)+EPS_LN);
    }
    const float g0=lng[l15], g1=lng[16+l15], g2=lng[32+l15], g3=lng[48+l15];
    const float q0=lnb[l15], q1=lnb[16+l15], q2=lnb[32+l15], q3=lnb[48+l15];
    // LN into own stripe; antidep vs own ay reads is program order.
    #pragma unroll
    for (int j=0;j<4;j++){
      const int rr_ = rbase + kg*4 + j;
      ybuf[rr_*LPAD +      l15] = f2bf_hw(fmaxf((tn0[j]-mu[j])*rs[j]*g0+q0, 0.f));
      ybuf[rr_*LPAD + 16 + l15] = f2bf_hw(fmaxf((tn1[j]-mu[j])*rs[j]*g1+q1, 0.f));
      ybuf[rr_*LPAD + 32 + l15] = f2bf_hw(fmaxf((tn2[j]-mu[j])*rs[j]*g2+q2, 0.f));
      ybuf[rr_*LPAD + 48 + l15] = f2bf_hw(fmaxf((tn3[j]-mu[j])*rs[j]*g3+q3, 0.f));
    }
  }

  // ---- prefetch GRU (col gcol) weight frags + biases; land during barrier ----
  const int gcol = w*16 + l15;
  const ushort_t* gih = wb + WO_GIH;
  const ushort_t* ghh = wb + WO_GHH;
  const short8 wr0 = LD8(gih + (      gcol)*64 + ko);
  const short8 wr1 = LD8(gih + (      gcol)*64 + 32 + ko);
  const short8 wz0 = LD8(gih + ( 64 + gcol)*64 + ko);
  const short8 wz1 = LD8(gih + ( 64 + gcol)*64 + 32 + ko);
  const short8 wn0 = LD8(gih + (128 + gcol)*64 + ko);
  const short8 wn1 = LD8(gih + (128 + gcol)*64 + 32 + ko);
  const short8 vr0 = LD8(ghh + (      gcol)*64 + ko);
  const short8 vr1 = LD8(ghh + (      gcol)*64 + 32 + ko);
  const short8 vz0 = LD8(ghh + ( 64 + gcol)*64 + ko);
  const short8 vz1 = LD8(ghh + ( 64 + gcol)*64 + 32 + ko);
  const short8 vn0 = LD8(ghh + (128 + gcol)*64 + ko);
  const short8 vn1 = LD8(ghh + (128 + gcol)*64 + 32 + ko);
  const float br  = gbih[gcol]     + gbhh[gcol];
  const float bz  = gbih[64+gcol]  + gbhh[64+gcol];
  const float bin_= gbih[128+gcol];
  const float bhn = gbhh[128+gcol];
  __syncthreads();   // ttl + all waves' stage visible

  // ---- GRU: col-tile per wave, 4 row-groups; h bf16 kept in regs ----
  us4 hkeep[4];
  #pragma unroll
  for (int rg=0; rg<4; rg++){
    const int ra = rg*16 + l15;
    const short8 at0 = LD8(&ybuf[ra*LPAD + ko]);
    const short8 at1 = LD8(&ybuf[ra*LPAD + 32 + ko]);
    const short8 bh0 = LD8(&hidl[ra*LPAD + ko]);
    const short8 bh1 = LD8(&hidl[ra*LPAD + 32 + ko]);
    f32x4 ar={0.f,0.f,0.f,0.f}, az=ar, an=ar, hn=ar;
    ar = MFMA(at0, wr0, ar);  ar = MFMA(at1, wr1, ar);
    ar = MFMA(bh0, vr0, ar);  ar = MFMA(bh1, vr1, ar);
    az = MFMA(at0, wz0, az);  az = MFMA(at1, wz1, az);
    az = MFMA(bh0, vz0, az);  az = MFMA(bh1, vz1, az);
    an = MFMA(at0, wn0, an);  an = MFMA(at1, wn1, an);
    hn = MFMA(bh0, vn0, hn);  hn = MFMA(bh1, vn1, hn);
    us4 hb4;
    #pragma unroll
    for (int j=0;j<4;j++){
      const int rloc = rg*16 + kg*4 + j;
      const float rrg = fsig(ar[j]+br);
      const float zzg = fsig(az[j]+bz);
      const float nng = ftanh(an[j]+bin_ + rrg*(hn[j]+bhn));
      const float hold = bf2f(hidl[rloc*LPAD + gcol]);
      const float hv = (1.f-zzg)*nng + zzg*hold;
      hb4[j] = f2bf_hw(hv);
    }
    hkeep[rg] = hb4;
  }

  __syncthreads();   // all waves done reading ttl/hidl -> ybuf reusable as hvl

  // ---- head weight frags + bias (latency hides under scatter + barrier) ----
  const short8 ow0 = LD8(wb + WO_OUT + l15*64 + ko);
  const short8 ow1 = LD8(wb + WO_OUT + l15*64 + 32 + ko);
  const float ob = (l15 < 12) ? outb[l15] : 0.f;

  #pragma unroll
  for (int rg=0; rg<4; rg++){
    #pragma unroll
    for (int j=0;j<4;j++)
      ybuf[(rg*16 + kg*4 + j)*LPAD + gcol] = hkeep[rg][j];
  }
  __syncthreads();   // hvl ready

  // ---- output head (wave-row decomp) ----
  const short8 av0 = LD8(&ybuf[rowA*LPAD + ko]);
  const short8 av1 = LD8(&ybuf[rowA*LPAD + 32 + ko]);
  f32x4 aa={0.f,0.f,0.f,0.f};
  aa = MFMA(av0, ow0, aa);
  aa = MFMA(av1, ow1, aa);
  if (l15 < 12){
    #pragma unroll
    for (int j=0;j<4;j++){
      const size_t rg_ = (size_t)blockIdx.x*64 + rbase + kg*4 + j;
      out_a[rg_*12 + l15] = aa[j] + ob;
    }
  }

  // ---- out_h coalesced writeback (dwordx4) from hvl ----
  {
    float* ohp = out_h + g;    // same mapping as stage: row sr, cols scb..scb+15
    #pragma unroll
    for (int i=0;i<4;i++){
      const us4 hq = *reinterpret_cast<const us4*>(&ybuf[sr*LPAD + scb + i*4]);
      float4 f;
      f.x = bf2f(hq.x); f.y = bf2f(hq.y); f.z = bf2f(hq.z); f.w = bf2f(hq.w);
      *reinterpret_cast<float4*>(ohp + i*4) = f;
    }
  }
}

extern "C" void kernel_launch(void* const* d_in, const int* in_sizes, int n_in,
                              void* d_out, int out_size, void* d_ws, size_t ws_size,
                              hipStream_t stream)
{
  (void)in_sizes; (void)n_in; (void)out_size; (void)ws_size;
  const float* inputs = (const float*)d_in[0];
  const float* hidden = (const float*)d_in[1];
  const int*   month  = (const int*)d_in[2];
  const float* jq     = (const float*)d_in[3];
  const float* wif    = (const float*)d_in[4];
  const float* whf    = (const float*)d_in[5];
  const float* bif    = (const float*)d_in[6];
  const float* bhf    = (const float*)d_in[7];
  const float* wib    = (const float*)d_in[8];
  const float* bib    = (const float*)d_in[10];
  const float* bhb    = (const float*)d_in[11];
  const float* fclw   = (const float*)d_in[12];
  const float* fclb   = (const float*)d_in[13];
  const float* projw  = (const float*)d_in[14];
  const float* convw  = (const float*)d_in[15];
  const float* convb  = (const float*)d_in[16];
  const float* bng    = (const float*)d_in[17];
  const float* bnb    = (const float*)d_in[18];
  const float* fc1w   = (const float*)d_in[19];
  const float* fc1b   = (const float*)d_in[20];
  const float* lng    = (const float*)d_in[21];
  const float* lnb    = (const float*)d_in[22];
  const float* gwih   = (const float*)d_in[23];
  const float* gwhh   = (const float*)d_in[24];
  const float* gbih   = (const float*)d_in[25];
  const float* gbhh   = (const float*)d_in[26];
  const float* outw   = (const float*)d_in[27];
  const float* outb   = (const float*)d_in[28];
  const float* lastw  = (const float*)d_in[29];

  float* ws  = (float*)d_ws;
  float* out = (float*)d_out;
  float* out_a  = out;
  float* out_h  = out + (size_t)NROWS*NACT;
  float* out_lg = out + (size_t)NROWS*(NACT+NHID);
  float* out_md = out + (size_t)NROWS*(NACT+NHID+4);
  ushort_t* wb = (ushort_t*)(ws + WS_WBF16);
  ushort_t* xgb = (ushort_t*)out_h;     // bf16 x_glb, block-local packed
  float* part1 = out_a;                 // [4096][64]
  float* part2 = out_a + (size_t)4096*64;

  hipLaunchKernelGGL(k1_lstm, dim3(NPROTO+4), dim3(256), 0, stream,
                     jq, wif, whf, bif, bhf, wib, bib, bhb,
                     fc1w, gwih, gwhh, outw, convw, wb, ws+WS_TH);
  hipLaunchKernelGGL(k2_proto, dim3(NPROTO), dim3(64), 0, stream,
                     ws+WS_TH, fclw, fclb, projw, convw, convb,
                     ws+WS_PV, ws+WS_PVSQ, ws+WS_CTAB, wb);
  hipLaunchKernelGGL(k3_mfma, dim3(NROWS/64), dim3(256), 0, stream,
                     inputs, month, ws+WS_PVSQ, ws+WS_CTAB, lastw, wb,
                     out_lg, out_md, xgb, part1, part2);
  hipLaunchKernelGGL(k4b_reduce, dim3(64), dim3(64), 0, stream,
                     part1, part2, (double*)(ws+WS_MID1), (double*)(ws+WS_MID2));
  hipLaunchKernelGGL(k5_finalize, dim3(1), dim3(64), 0, stream,
                     (const double*)(ws+WS_MID1), (const double*)(ws+WS_MID2),
                     bng, bnb, ws+WS_BNSC, ws+WS_BNSH);
  hipLaunchKernelGGL(k6_mfma, dim3(NROWS/64), dim3(256), 0, stream,
                     xgb, hidden, ws+WS_BNSC, ws+WS_BNSH, fc1b, lng, lnb,
                     gbih, gbhh, outb, wb, out_a, out_h);
}

// Round 8
// 140.083 us; speedup vs baseline: 2.0722x; 1.0673x over previous
//
#include <hip/hip_runtime.h>
#include <cmath>

#define NHID 64
#define NMONTH 16384
#define NAGENT 16
#define NROWS (NMONTH*NAGENT)   // 262144
#define NPROTO 24
#define TSEQ 32
#define NACT 12
#define EPS_P  1e-4f
#define EPS_BN 1e-5f
#define EPS_LN 1e-5f

typedef __attribute__((ext_vector_type(8))) short short8;
typedef __attribute__((ext_vector_type(4))) float f32x4;
typedef __attribute__((ext_vector_type(4))) unsigned short us4;
typedef __attribute__((ext_vector_type(8))) unsigned short us8;
typedef unsigned short ushort_t;

#define MFMA(a,b,c) __builtin_amdgcn_mfma_f32_16x16x32_bf16(a,b,c,0,0,0)
#define LPAD 68   // k6 LDS row stride (ushorts): 136B = 34 dwords -> 2-way (free)
#define LDSFENCE() asm volatile("s_waitcnt lgkmcnt(0)" ::: "memory")
#define LD8(P) (*reinterpret_cast<const short8*>(P))

typedef const __attribute__((address_space(1))) void* gvp;
typedef __attribute__((address_space(3))) void* lvp;

// ---- ws layout (float offsets) ----
#define WS_PV     3072     // [24][64]  f32 (unused now, reserved)
#define WS_PVSQ   4608     // [24] (pad 32)
#define WS_CTAB   4640     // [24][64]
#define WS_MID1   6176     // [64][64] f64 -> 8192 floats
#define WS_MID2   14368    // [64][64] f64
#define WS_BNSC   22560    // [64]
#define WS_BNSH   22624    // [64]
#define WS_WBF16  22688    // ushort region below
#define WO_FC1   0         // fc1w bf16 [64][64]
#define WO_GIH   4096      // gwih bf16 [192][64]
#define WO_GHH   16384     // gwhh bf16 [192][64]
#define WO_OUT   28672     // outw bf16 [16][64] (rows 12-15 zero)
#define WO_PV    29696     // pv bf16 [32][64] (rows 24-31 zero)
#define WO_CVX   31744     // convw[:, :64] bf16 [64][64]

__device__ __forceinline__ float sigf(float x){ return 1.0f/(1.0f+expf(-x)); }
__device__ __forceinline__ float fsig(float x){
  return __builtin_amdgcn_rcpf(1.f + __expf(-x));
}
__device__ __forceinline__ float ftanh(float x){
  return 1.f - 2.f*__builtin_amdgcn_rcpf(1.f + __expf(2.f*x));
}
__device__ __forceinline__ ushort_t f2bf(float f){
  unsigned u = __builtin_bit_cast(unsigned, f);
  u += 0x7FFFu + ((u>>16)&1u);           // round-to-nearest-even
  return (ushort_t)(u>>16);
}
__device__ __forceinline__ float bf2f(ushort_t b){
  return __builtin_bit_cast(float, ((unsigned)b)<<16);
}
// HW packed f32x2 -> bf16x2 (RNE), 1 VALU instr
__device__ __forceinline__ unsigned pk2bf(float a, float b){
  unsigned d;
  asm("v_cvt_pk_bf16_f32 %0, %1, %2" : "=v"(d) : "v"(a), "v"(b));
  return d;
}
// 1-instr scalar f32->bf16 (low half of cvt_pk)
__device__ __forceinline__ ushort_t f2bf_hw(float x){
  unsigned d;
  asm("v_cvt_pk_bf16_f32 %0, %1, %2" : "=v"(d) : "v"(x), "v"(x));
  return (ushort_t)d;
}
// build bf16 A-frag (8 elems = logical f32 cols base*4 .. base*4+7) for row ra
// from chunk-swizzled f32 LDS slab hraw[64][64] (phys chunk = logical ^ (ra&15))
__device__ __forceinline__ short8 hfrag(const float* hraw, int ra, int base){
  const int r15 = ra & 15;
  const float4 a = *reinterpret_cast<const float4*>(&hraw[ra*64 + (((base  )^r15)<<2)]);
  const float4 b = *reinterpret_cast<const float4*>(&hraw[ra*64 + (((base+1)^r15)<<2)]);
  uint4 u; u.x=pk2bf(a.x,a.y); u.y=pk2bf(a.z,a.w); u.z=pk2bf(b.x,b.y); u.w=pk2bf(b.z,b.w);
  return __builtin_bit_cast(short8, u);
}

// ---------------- K1: biLSTM + proto pipeline (blocks 0-23), weight->bf16 (blocks 24-27) ----------------
// k2 fused in: block p computes th[p] via LSTM then immediately fcl->proj->
// ctab/pvsq/PV-bf16 for proto p (no th round-trip, one fewer launch).
__global__ __launch_bounds__(256) void k1_lstm(
    const float* __restrict__ jq,
    const float* __restrict__ wif, const float* __restrict__ whf,
    const float* __restrict__ bif, const float* __restrict__ bhf,
    const float* __restrict__ wib, const float* __restrict__ bib, const float* __restrict__ bhb,
    const float* __restrict__ fclw, const float* __restrict__ fclb,
    const float* __restrict__ projw, const float* __restrict__ convb,
    const float* __restrict__ fc1w, const float* __restrict__ gwih,
    const float* __restrict__ gwhh, const float* __restrict__ outw,
    const float* __restrict__ convw, ushort_t* __restrict__ wb,
    float* __restrict__ pvsq, float* __restrict__ ctab)
{
  __shared__ float hs[NHID];
  __shared__ float gs[4*NHID];
  if (blockIdx.x >= NPROTO){
    const int tt = (blockIdx.x - NPROTO)*256 + threadIdx.x;   // 0..1023
    for (int i=tt;i<4096;i+=1024)  wb[WO_FC1+i]=f2bf(fc1w[i]);
    for (int i=tt;i<12288;i+=1024){ wb[WO_GIH+i]=f2bf(gwih[i]); wb[WO_GHH+i]=f2bf(gwhh[i]); }
    for (int i=tt;i<1024;i+=1024)  wb[WO_OUT+i] = (i<768)? f2bf(outw[i]) : (ushort_t)0;
    for (int i=tt;i<4096;i+=1024)  wb[WO_CVX+i] = f2bf(convw[(i>>6)*128 + (i&63)]);
    return;
  }
  const int p = blockIdx.x;
  const int j = threadIdx.x;
  float wh[NHID];
  #pragma unroll
  for (int k=0;k<NHID;k++) wh[k] = whf[j*NHID+k];
  const float wi0=wif[j*3], wi1=wif[j*3+1], wi2=wif[j*3+2];
  const float bj = bif[j]+bhf[j];
  float c = 0.f;
  if (j < NHID) hs[j] = 0.f;
  __syncthreads();
  for (int t=0;t<TSEQ;t++){
    const float x0=jq[(p*TSEQ+t)*3], x1=jq[(p*TSEQ+t)*3+1], x2=jq[(p*TSEQ+t)*3+2];
    float g = wi0*x0+wi1*x1+wi2*x2+bj;
    #pragma unroll
    for (int k=0;k<NHID;k++) g += wh[k]*hs[k];
    __syncthreads();
    gs[j] = g;
    __syncthreads();
    if (j < NHID){
      const float gi=gs[j], gf=gs[NHID+j], gg=gs[2*NHID+j], go=gs[3*NHID+j];
      c = sigf(gf)*c + sigf(gi)*tanhf(gg);
      hs[j] = sigf(go)*tanhf(c);
    }
    __syncthreads();
  }
  // backward dir: one step on x[:, T-1]
  const float x0=jq[(p*TSEQ+TSEQ-1)*3], x1=jq[(p*TSEQ+TSEQ-1)*3+1], x2=jq[(p*TSEQ+TSEQ-1)*3+2];
  const float gb = wib[j*3]*x0 + wib[j*3+1]*x1 + wib[j*3+2]*x2 + bib[j]+bhb[j];
  __syncthreads();
  gs[j] = gb;
  __syncthreads();
  // th = [h_f | h_b] assembled in gs[0..127]
  if (j < NHID){
    const float gi=gs[j], gg=gs[2*NHID+j], go=gs[3*NHID+j];
    const float cb = sigf(gi)*tanhf(gg);
    const float hb = sigf(go)*tanhf(cb);
    const float hf = hs[j];
    __syncthreads();                 // all lanes done reading gs gates
    gs[j]      = hf;
    gs[NHID+j] = hb;
  } else {
    __syncthreads();
  }
  __syncthreads();

  // ---- fused k2: fcl -> relu -> proj -> ctab/pvsq/PV-bf16 ----
  if (j < NHID){
    float acc = fclb[j];
    for (int k=0;k<2*NHID;k++) acc += gs[k]*fclw[j*2*NHID+k];
    hs[j] = fmaxf(acc, 0.f);         // t1
  }
  __syncthreads();
  if (j < NHID){
    float pvh = 0.f;
    for (int k=0;k<NHID;k++) pvh += hs[k]*projw[j*NHID+k];
    gs[2*NHID+j] = pvh;              // pvr
    wb[WO_PV + p*64 + j] = f2bf(pvh);
    if (p==0){
      #pragma unroll
      for (int r=24;r<32;r++) wb[WO_PV + r*64 + j] = (ushort_t)0;
    }
  }
  __syncthreads();
  if (j < NHID){
    const float* pvr = gs + 2*NHID;
    float ct = convb[j];
    for (int k=0;k<NHID;k++) ct += pvr[k]*convw[j*2*NHID+NHID+k];
    ctab[p*NHID+j] = ct;
    if (j==0){
      float s=0.f;
      for (int k=0;k<NHID;k++) s += pvr[k]*pvr[k];
      pvsq[p]=s;
    }
  }
}

// ---------------- K3: MFMA distances+logits+argmax+conv + BN partials ----------------
// stage/distances/logits/argmax wave-local (fences); ONE barrier before the
// cross-wave conv. Stage loads issued before weight-frag loads.
__global__ __launch_bounds__(256) void k3_mfma(
    const float* __restrict__ inp, const int* __restrict__ month,
    const float* __restrict__ pvsq, const float* __restrict__ ctab,
    const float* __restrict__ lastw, const ushort_t* __restrict__ wb,
    float* __restrict__ out_logits, float* __restrict__ out_md,
    ushort_t* __restrict__ xgb, float* __restrict__ part1, float* __restrict__ part2)
{
  __shared__ ushort_t xl[64*72];     // x rows bf16
  __shared__ float insql[64];        // fp32 row ||x||^2
  __shared__ float pal[64*26];       // prototype activations (wave-local use)

  const int t = threadIdx.x;
  const int w = t>>6, lane = t&63;
  const int l15 = lane&15, kg = lane>>4, ko = kg*8;
  const int gcol = w*16 + l15;
  const int rbase = w*16;
  const int rowA = rbase + l15;
  const size_t rowblk = (size_t)blockIdx.x*64;

  // ---- stage loads FIRST (oldest in vmcnt queue) ----
  const int sr = t>>2, scb = (t&3)*16;
  float4 xr[4];
  #pragma unroll
  for (int i=0;i<4;i++)
    xr[i] = *reinterpret_cast<const float4*>(inp + (rowblk + sr)*64 + scb + i*4);
  const int mo = month[blockIdx.x*4 + w];

  // ---- weight fragments (land under stage processing) ----
  const short8 pv0a = LD8(wb + WO_PV + l15*64 + ko);
  const short8 pv0b = LD8(wb + WO_PV + l15*64 + 32 + ko);
  const short8 pv1a = LD8(wb + WO_PV + (16+l15)*64 + ko);
  const short8 pv1b = LD8(wb + WO_PV + (16+l15)*64 + 32 + ko);
  const float pq0 = pvsq[l15];
  const float pq1 = (l15<8)? pvsq[16+l15] : 0.f;
  const int season = ((mo+10)%12)/3;

  // ---- stage x -> bf16 LDS + fp32 insq (wave-local rows) ----
  {
    float ss = 0.f;
    #pragma unroll
    for (int i=0;i<4;i++){
      const float4 xv = xr[i];
      ss += xv.x*xv.x + xv.y*xv.y + xv.z*xv.z + xv.w*xv.w;
      uint2 yy; yy.x = pk2bf(xv.x, xv.y); yy.y = pk2bf(xv.z, xv.w);
      *reinterpret_cast<uint2*>(&xl[sr*72 + scb + i*4]) = yy;
    }
    ss += __shfl_xor(ss,1,4);
    ss += __shfl_xor(ss,2,4);
    if ((t&3)==0) insql[sr] = ss;
  }
  LDSFENCE();

  const short8 ax0 = LD8(&xl[rowA*72+ko]);
  const short8 ax1 = LD8(&xl[rowA*72+32+ko]);

  // ---- distances: xp = X . PV^T (wave-row decomp) ----
  f32x4 d0={0.f,0.f,0.f,0.f}, d1=d0;
  d0 = MFMA(ax0, pv0a, d0);
  d0 = MFMA(ax1, pv0b, d0);
  d1 = MFMA(ax0, pv1a, d1);
  d1 = MFMA(ax1, pv1b, d1);
  {
    #pragma unroll
    for (int j=0;j<4;j++){
      const int rloc = rbase + kg*4 + j;
      const float iq = insql[rloc];
      const float md0 = iq + pq0 - 2.f*d0[j];
      out_md[(rowblk+rloc)*24 + l15] = md0;
      pal[rloc*26 + l15] = __logf(md0+1.f) - __logf(md0+EPS_P);
      const float md1 = iq + pq1 - 2.f*d1[j];
      const float pa1 = __logf(md1+1.f) - __logf(md1+EPS_P);
      if (l15<8){
        out_md[(rowblk+rloc)*24 + 16+l15] = md1;
        pal[rloc*26 + 16+l15] = pa1;
      }
    }
  }
  LDSFENCE();   // own pal rows committed

  // ---- logits (wave-local rows) ----
  {
    const int r2 = rbase + (lane>>2), c = lane&3;
    float lgv = 0.f;
    #pragma unroll
    for (int p=0;p<24;p++) lgv += pal[r2*26+p]*lastw[c*24+p];
    out_logits[(rowblk+r2)*4 + c] = lgv;
  }

  // ---- month argmax over 6 seasonal protos (in-register result) ----
  int qsw;
  {
    float simv = -3.4e38f;
    const int j6 = lane & 7;
    if (j6 < 6){
      simv = 0.f;
      const int sp = season*6 + j6;
      #pragma unroll
      for (int i=0;i<16;i++) simv += pal[(rbase+i)*26 + sp];
    }
    int bidx = j6;
    { const float ov=__shfl_xor(simv,1,8); const int oi=__shfl_xor(bidx,1,8);
      if (ov>simv || (ov==simv && oi<bidx)){ simv=ov; bidx=oi; } }
    { const float ov=__shfl_xor(simv,2,8); const int oi=__shfl_xor(bidx,2,8);
      if (ov>simv || (ov==simv && oi<bidx)){ simv=ov; bidx=oi; } }
    { const float ov=__shfl_xor(simv,4,8); const int oi=__shfl_xor(bidx,4,8);
      if (ov>simv || (ov==simv && oi<bidx)){ simv=ov; bidx=oi; } }
    qsw = season*6 + bidx;
  }

  // ---- conv weight frags (consumed after barrier; latency hides there) ----
  const short8 cw0  = LD8(wb + WO_CVX + gcol*64 + ko);
  const short8 cw1  = LD8(wb + WO_CVX + gcol*64 + 32 + ko);
  __syncthreads();   // all waves' xl visible for cross-wave conv

  // ---- conv: col-tile per wave, weights loop-invariant; bf16 block-local out ----
  ushort_t* xgblk = xgb + (size_t)blockIdx.x*8192;
  const float cg = ctab[qsw*64 + gcol];
  float s1=0.f, s2=0.f;
  #pragma unroll
  for (int rg=0; rg<4; rg++){
    const int ra = rg*16 + l15;
    const short8 bx0 = LD8(&xl[ra*72+ko]);
    const short8 bx1 = LD8(&xl[ra*72+32+ko]);
    f32x4 ac={0.f,0.f,0.f,0.f};
    ac = MFMA(bx0, cw0, ac);
    ac = MFMA(bx1, cw1, ac);
    #pragma unroll
    for (int j=0;j<4;j++){
      const int rloc = rg*16 + kg*4 + j;
      const float v = ac[j] + cg;
      xgblk[rloc*64 + gcol] = f2bf_hw(v);
      s1 += v; s2 += v*v;
    }
  }
  s1 += __shfl_xor(s1,16); s1 += __shfl_xor(s1,32);
  s2 += __shfl_xor(s2,16); s2 += __shfl_xor(s2,32);
  if (kg==0){
    part1[(size_t)blockIdx.x*64 + gcol] = s1;
    part2[(size_t)blockIdx.x*64 + gcol] = s2;
  }
}

// ---------------- K4b: partials [4096][64] -> mid [64][64] f64 ----------------
__global__ __launch_bounds__(64) void k4b_reduce(
    const float* __restrict__ part1, const float* __restrict__ part2,
    double* __restrict__ mid1, double* __restrict__ mid2)
{
  const int i = blockIdx.x, c = threadIdx.x;
  double s1=0.0, s2=0.0;
  for (int b=i*64; b<i*64+64; b++){
    s1 += (double)part1[b*64+c];
    s2 += (double)part2[b*64+c];
  }
  mid1[i*64+c]=s1; mid2[i*64+c]=s2;
}

// ---------------- K5: BN stats finalize ----------------
__global__ __launch_bounds__(64) void k5_finalize(
    const double* __restrict__ mid1, const double* __restrict__ mid2,
    const float* __restrict__ bng, const float* __restrict__ bnb,
    float* __restrict__ bnsc, float* __restrict__ bnsh)
{
  const int f = threadIdx.x;
  double s1=0.0, s2=0.0;
  for (int i=0;i<64;i++){ s1+=mid1[i*64+f]; s2+=mid2[i*64+f]; }
  const double mu = s1 / (double)NROWS;
  double var = s2/(double)NROWS - mu*mu;
  if (var < 0.0) var = 0.0;
  const float sc = bng[f] * (float)(1.0/sqrt(var + (double)EPS_BN));
  bnsc[f]=sc;
  bnsh[f]=bnb[f]-(float)mu*sc;
}

// ---------------- K6: MFMA  BN->fc1->LN->GRU->head ----------------
// hidden staged via async global_load_lds DMA into a linear f32 LDS slab
// (source-address chunk-swizzled: phys chunk = logical ^ (row&15)); the DMA
// drains at the pre-GRU barrier, so HBM latency hides under stage+fc1+LN.
// GRU builds bf16 A-frags from f32 LDS (cvt_pk); 'hold' is exact f32.
__global__ __launch_bounds__(256) void k6_mfma(
    const ushort_t* __restrict__ xgb, const float* __restrict__ hidden,
    const float* __restrict__ bnsc, const float* __restrict__ bnsh,
    const float* __restrict__ fc1b, const float* __restrict__ lng, const float* __restrict__ lnb,
    const float* __restrict__ gbih, const float* __restrict__ gbhh,
    const float* __restrict__ outb,
    const ushort_t* __restrict__ wb,
    float* __restrict__ out_a, float* __restrict__ out_h)
{
  __shared__ ushort_t ybuf[64*LPAD];   // y -> ttl -> hvl (phased reuse)
  __shared__ float hraw[64*64];        // f32 hidden slab, chunk-swizzled
  const int t = threadIdx.x;
  const int lane = t & 63, w = t >> 6;
  const int l15 = lane & 15, kg = lane >> 4;
  const int ko = kg*8;
  const int rbase = w*16;
  const int rowA = rbase + l15;
  const int sr = t>>2, scb = (t&3)*16;

  // ---- stage loads FIRST (oldest in vmcnt queue) ----
  const ushort_t* xgp = xgb + (size_t)blockIdx.x*8192 + sr*64 + scb;
  const us8 xv0 = *reinterpret_cast<const us8*>(xgp);
  const us8 xv1 = *reinterpret_cast<const us8*>(xgp+8);

  // ---- fc1 weight frags (land under stage processing) ----
  const short8 f0a = LD8(wb + WO_FC1 + ( 0+l15)*64 + ko);
  const short8 f0b = LD8(wb + WO_FC1 + ( 0+l15)*64 + 32 + ko);
  const short8 f1a = LD8(wb + WO_FC1 + (16+l15)*64 + ko);
  const short8 f1b = LD8(wb + WO_FC1 + (16+l15)*64 + 32 + ko);
  const short8 f2a = LD8(wb + WO_FC1 + (32+l15)*64 + ko);
  const short8 f2b = LD8(wb + WO_FC1 + (32+l15)*64 + 32 + ko);
  const short8 f3a = LD8(wb + WO_FC1 + (48+l15)*64 + ko);
  const short8 f3b = LD8(wb + WO_FC1 + (48+l15)*64 + 32 + ko);

  // ---- async DMA: hidden (16 KB f32) -> hraw, 16 x 1KB, source swizzled ----
  // issued AFTER the loads above so their vmcnt waits leave the DMAs in flight;
  // consumed only after the pre-GRU barrier (which drains vmcnt to 0).
  {
    const float* hbase = hidden + (size_t)blockIdx.x*4096;
    #pragma unroll
    for (int k=0;k<4;k++){
      const int c = (w*4+k)*64 + lane;          // 16B-chunk index
      const int row = c>>4, ccp = c&15;
      const float* src = hbase + row*64 + ((ccp ^ (row&15))<<2);
      float* dst = &hraw[(w*4+k)*256];          // wave-uniform base
      __builtin_amdgcn_global_load_lds((gvp)src, (lvp)dst, 16, 0, 0);
    }
  }

  // ---- stage: BN+relu(x_bf16) -> bf16 LDS (wave-local rows) ----
  {
    float xf[16];
    #pragma unroll
    for (int e=0;e<8;e++){ xf[e]=bf2f(xv0[e]); xf[8+e]=bf2f(xv1[e]); }
    #pragma unroll
    for (int i=0;i<4;i++){
      const float4 sc = *reinterpret_cast<const float4*>(bnsc + scb + i*4);
      const float4 sh = *reinterpret_cast<const float4*>(bnsh + scb + i*4);
      const float y0 = fmaxf(xf[4*i  ]*sc.x+sh.x, 0.f);
      const float y1 = fmaxf(xf[4*i+1]*sc.y+sh.y, 0.f);
      const float y2 = fmaxf(xf[4*i+2]*sc.z+sh.z, 0.f);
      const float y3 = fmaxf(xf[4*i+3]*sc.w+sh.w, 0.f);
      uint2 yy; yy.x = pk2bf(y0,y1); yy.y = pk2bf(y2,y3);
      *reinterpret_cast<uint2*>(&ybuf[sr*LPAD + scb + i*4]) = yy;
    }
  }
  LDSFENCE();   // own stage rows committed (fc1 reads own rows only)

  const short8 ay0 = LD8(&ybuf[rowA*LPAD + ko]);
  const short8 ay1 = LD8(&ybuf[rowA*LPAD + 32 + ko]);

  // ---- fc1 (wave-row decomp, preloaded frags) ----
  f32x4 ac0={0.f,0.f,0.f,0.f}, ac1=ac0, ac2=ac0, ac3=ac0;
  ac0 = MFMA(ay0, f0a, ac0);  ac0 = MFMA(ay1, f0b, ac0);
  ac1 = MFMA(ay0, f1a, ac1);  ac1 = MFMA(ay1, f1b, ac1);
  ac2 = MFMA(ay0, f2a, ac2);  ac2 = MFMA(ay1, f2b, ac2);
  ac3 = MFMA(ay0, f3a, ac3);  ac3 = MFMA(ay1, f3b, ac3);
  {
    const float b0=fc1b[l15], b1=fc1b[16+l15], b2=fc1b[32+l15], b3=fc1b[48+l15];
    float tn0[4], tn1[4], tn2[4], tn3[4], mu[4], rs[4];
    #pragma unroll
    for (int j=0;j<4;j++){ tn0[j]=ac0[j]+b0; tn1[j]=ac1[j]+b1; tn2[j]=ac2[j]+b2; tn3[j]=ac3[j]+b3; }
    #pragma unroll
    for (int j=0;j<4;j++){
      float s = tn0[j]+tn1[j]+tn2[j]+tn3[j];
      s += __shfl_xor(s,1,16); s += __shfl_xor(s,2,16);
      s += __shfl_xor(s,4,16); s += __shfl_xor(s,8,16);
      mu[j] = s*(1.f/64.f);
    }
    #pragma unroll
    for (int j=0;j<4;j++){
      const float d0_=tn0[j]-mu[j], d1_=tn1[j]-mu[j], d2_=tn2[j]-mu[j], d3_=tn3[j]-mu[j];
      float v = d0_*d0_+d1_*d1_+d2_*d2_+d3_*d3_;
      v += __shfl_xor(v,1,16); v += __shfl_xor(v,2,16);
      v += __shfl_xor(v,4,16); v += __shfl_xor(v,8,16);
      rs[j] = 1.f/sqrtf(v*(1.f/64.f)+EPS_LN);
    }
    const float g0=lng[l15], g1=lng[16+l15], g2=lng[32+l15], g3=lng[48+l15];
    const float q0=lnb[l15], q1=lnb[16+l15], q2=lnb[32+l15], q3=lnb[48+l15];
    // LN into own stripe; antidep vs own ay reads is program order.
    #pragma unroll
    for (int j=0;j<4;j++){
      const int rr_ = rbase + kg*4 + j;
      ybuf[rr_*LPAD +      l15] = f2bf_hw(fmaxf((tn0[j]-mu[j])*rs[j]*g0+q0, 0.f));
      ybuf[rr_*LPAD + 16 + l15] = f2bf_hw(fmaxf((tn1[j]-mu[j])*rs[j]*g1+q1, 0.f));
      ybuf[rr_*LPAD + 32 + l15] = f2bf_hw(fmaxf((tn2[j]-mu[j])*rs[j]*g2+q2, 0.f));
      ybuf[rr_*LPAD + 48 + l15] = f2bf_hw(fmaxf((tn3[j]-mu[j])*rs[j]*g3+q3, 0.f));
    }
  }

  // ---- prefetch GRU (col gcol) weight frags + biases; land during barrier ----
  const int gcol = w*16 + l15;
  const ushort_t* gih = wb + WO_GIH;
  const ushort_t* ghh = wb + WO_GHH;
  const short8 wr0 = LD8(gih + (      gcol)*64 + ko);
  const short8 wr1 = LD8(gih + (      gcol)*64 + 32 + ko);
  const short8 wz0 = LD8(gih + ( 64 + gcol)*64 + ko);
  const short8 wz1 = LD8(gih + ( 64 + gcol)*64 + 32 + ko);
  const short8 wn0 = LD8(gih + (128 + gcol)*64 + ko);
  const short8 wn1 = LD8(gih + (128 + gcol)*64 + 32 + ko);
  const short8 vr0 = LD8(ghh + (      gcol)*64 + ko);
  const short8 vr1 = LD8(ghh + (      gcol)*64 + 32 + ko);
  const short8 vz0 = LD8(ghh + ( 64 + gcol)*64 + ko);
  const short8 vz1 = LD8(ghh + ( 64 + gcol)*64 + 32 + ko);
  const short8 vn0 = LD8(ghh + (128 + gcol)*64 + ko);
  const short8 vn1 = LD8(ghh + (128 + gcol)*64 + 32 + ko);
  const float bir=gbih[gcol],     bhr=gbhh[gcol];
  const float biz=gbih[64+gcol],  bhz=gbhh[64+gcol];
  const float bin_=gbih[128+gcol],bhn=gbhh[128+gcol];
  __syncthreads();   // ttl + all waves' stage visible; hraw DMA drained

  // ---- GRU: col-tile per wave, 4 row-groups; h bf16 kept in regs ----
  us4 hkeep[4];
  #pragma unroll
  for (int rg=0; rg<4; rg++){
    const int ra = rg*16 + l15;
    const short8 at0 = LD8(&ybuf[ra*LPAD + ko]);
    const short8 at1 = LD8(&ybuf[ra*LPAD + 32 + ko]);
    const short8 bh0 = hfrag(hraw, ra, 2*kg);      // cols ko..ko+7
    const short8 bh1 = hfrag(hraw, ra, 8+2*kg);    // cols 32+ko..32+ko+7
    f32x4 ar={0.f,0.f,0.f,0.f}, az=ar, an=ar, hn=ar;
    ar = MFMA(at0, wr0, ar);  ar = MFMA(at1, wr1, ar);
    ar = MFMA(bh0, vr0, ar);  ar = MFMA(bh1, vr1, ar);
    az = MFMA(at0, wz0, az);  az = MFMA(at1, wz1, az);
    az = MFMA(bh0, vz0, az);  az = MFMA(bh1, vz1, az);
    an = MFMA(at0, wn0, an);  an = MFMA(at1, wn1, an);
    hn = MFMA(bh0, vn0, hn);  hn = MFMA(bh1, vn1, hn);
    us4 hb4;
    #pragma unroll
    for (int j=0;j<4;j++){
      const int rloc = rg*16 + kg*4 + j;
      const size_t rg_ = (size_t)blockIdx.x*64 + rloc;
      const float rrg = fsig(ar[j]+bir+bhr);
      const float zzg = fsig(az[j]+biz+bhz);
      const float nng = ftanh(an[j]+bin_ + rrg*(hn[j]+bhn));
      const float hold = hraw[rloc*64 + ((((gcol>>2)^(rloc&15))<<2) + (gcol&3))];
      const float hv = (1.f-zzg)*nng + zzg*hold;
      out_h[rg_*64 + gcol] = hv;
      hb4[j] = f2bf_hw(hv);
    }
    hkeep[rg] = hb4;
  }

  // ---- head weight frags + bias: issue now, latency hides under the barriers ----
  const short8 ow0 = LD8(wb + WO_OUT + l15*64 + ko);
  const short8 ow1 = LD8(wb + WO_OUT + l15*64 + 32 + ko);
  const float ob = (l15 < 12) ? outb[l15] : 0.f;

  __syncthreads();   // all waves done reading ttl/hraw -> ybuf reusable as hvl
  #pragma unroll
  for (int rg=0; rg<4; rg++){
    #pragma unroll
    for (int j=0;j<4;j++)
      ybuf[(rg*16 + kg*4 + j)*LPAD + gcol] = hkeep[rg][j];
  }
  __syncthreads();   // hvl ready

  // ---- output head (wave-row decomp) ----
  const short8 av0 = LD8(&ybuf[rowA*LPAD + ko]);
  const short8 av1 = LD8(&ybuf[rowA*LPAD + 32 + ko]);
  f32x4 aa={0.f,0.f,0.f,0.f};
  aa = MFMA(av0, ow0, aa);
  aa = MFMA(av1, ow1, aa);
  if (l15 < 12){
    #pragma unroll
    for (int j=0;j<4;j++){
      const size_t rg_ = (size_t)blockIdx.x*64 + rbase + kg*4 + j;
      out_a[rg_*12 + l15] = aa[j] + ob;
    }
  }
}

extern "C" void kernel_launch(void* const* d_in, const int* in_sizes, int n_in,
                              void* d_out, int out_size, void* d_ws, size_t ws_size,
                              hipStream_t stream)
{
  (void)in_sizes; (void)n_in; (void)out_size; (void)ws_size;
  const float* inputs = (const float*)d_in[0];
  const float* hidden = (const float*)d_in[1];
  const int*   month  = (const int*)d_in[2];
  const float* jq     = (const float*)d_in[3];
  const float* wif    = (const float*)d_in[4];
  const float* whf    = (const float*)d_in[5];
  const float* bif    = (const float*)d_in[6];
  const float* bhf    = (const float*)d_in[7];
  const float* wib    = (const float*)d_in[8];
  const float* bib    = (const float*)d_in[10];
  const float* bhb    = (const float*)d_in[11];
  const float* fclw   = (const float*)d_in[12];
  const float* fclb   = (const float*)d_in[13];
  const float* projw  = (const float*)d_in[14];
  const float* convw  = (const float*)d_in[15];
  const float* convb  = (const float*)d_in[16];
  const float* bng    = (const float*)d_in[17];
  const float* bnb    = (const float*)d_in[18];
  const float* fc1w   = (const float*)d_in[19];
  const float* fc1b   = (const float*)d_in[20];
  const float* lng    = (const float*)d_in[21];
  const float* lnb    = (const float*)d_in[22];
  const float* gwih   = (const float*)d_in[23];
  const float* gwhh   = (const float*)d_in[24];
  const float* gbih   = (const float*)d_in[25];
  const float* gbhh   = (const float*)d_in[26];
  const float* outw   = (const float*)d_in[27];
  const float* outb   = (const float*)d_in[28];
  const float* lastw  = (const float*)d_in[29];

  float* ws  = (float*)d_ws;
  float* out = (float*)d_out;
  float* out_a  = out;
  float* out_h  = out + (size_t)NROWS*NACT;
  float* out_lg = out + (size_t)NROWS*(NACT+NHID);
  float* out_md = out + (size_t)NROWS*(NACT+NHID+4);
  ushort_t* wb = (ushort_t*)(ws + WS_WBF16);
  ushort_t* xgb = (ushort_t*)out_h;     // bf16 x_glb, block-local packed
  float* part1 = out_a;                 // [4096][64]
  float* part2 = out_a + (size_t)4096*64;

  hipLaunchKernelGGL(k1_lstm, dim3(NPROTO+4), dim3(256), 0, stream,
                     jq, wif, whf, bif, bhf, wib, bib, bhb,
                     fclw, fclb, projw, convb,
                     fc1w, gwih, gwhh, outw, convw, wb,
                     ws+WS_PVSQ, ws+WS_CTAB);
  hipLaunchKernelGGL(k3_mfma, dim3(NROWS/64), dim3(256), 0, stream,
                     inputs, month, ws+WS_PVSQ, ws+WS_CTAB, lastw, wb,
                     out_lg, out_md, xgb, part1, part2);
  hipLaunchKernelGGL(k4b_reduce, dim3(64), dim3(64), 0, stream,
                     part1, part2, (double*)(ws+WS_MID1), (double*)(ws+WS_MID2));
  hipLaunchKernelGGL(k5_finalize, dim3(1), dim3(64), 0, stream,
                     (const double*)(ws+WS_MID1), (const double*)(ws+WS_MID2),
                     bng, bnb, ws+WS_BNSC, ws+WS_BNSH);
  hipLaunchKernelGGL(k6_mfma, dim3(NROWS/64), dim3(256), 0, stream,
                     xgb, hidden, ws+WS_BNSC, ws+WS_BNSH, fc1b, lng, lnb,
                     gbih, gbhh, outb, wb, out_a, out_h);
}